// Round 10
// baseline (859.153 us; speedup 1.0000x reference)
//
#include <hip/hip_runtime.h>

typedef float f32x4  __attribute__((ext_vector_type(4)));
typedef int   i32x4  __attribute__((ext_vector_type(4)));
typedef int   i32x16 __attribute__((ext_vector_type(16)));
typedef char  s8x16  __attribute__((ext_vector_type(16)));

#define GAS __attribute__((address_space(1)))
#define LAS __attribute__((address_space(3)))
#define SBAR __builtin_amdgcn_sched_barrier(0)

constexpr int M = 8192;       // B*S
constexpr int N = 16384;      // D_OUT
constexpr int K = 4096;       // D_IN
constexpr long long NX = (long long)M * K;   // 33,554,432
constexpr long long NW = (long long)N * K;   // 67,108,864
constexpr int NPART = 2048;
constexpr int NKT = 32;       // K / 128

// ---------------- reductions ----------------

__global__ void reduce_absmax_kernel(const float* __restrict__ x,
                                     unsigned* __restrict__ gmax, int n4) {
  float m = 0.f;
  int stride = gridDim.x * blockDim.x;
  for (int i = blockIdx.x * blockDim.x + threadIdx.x; i < n4; i += stride) {
    f32x4 v = *(const f32x4*)(x + (size_t)i * 4);
    m = fmaxf(m, fmaxf(fmaxf(fabsf(v[0]), fabsf(v[1])),
                       fmaxf(fabsf(v[2]), fabsf(v[3]))));
  }
#pragma unroll
  for (int off = 32; off > 0; off >>= 1) m = fmaxf(m, __shfl_down(m, off));
  __shared__ float sm[4];
  int lane = threadIdx.x & 63, wid = threadIdx.x >> 6;
  if (lane == 0) sm[wid] = m;
  __syncthreads();
  if (threadIdx.x == 0) {
    m = fmaxf(fmaxf(sm[0], sm[1]), fmaxf(sm[2], sm[3]));
    atomicMax(gmax, __float_as_uint(m));  // |x| >= 0: bit-order == float-order
  }
}

__global__ void reduce_abssum_kernel(const float* __restrict__ w,
                                     float* __restrict__ partials, int n4) {
  float s = 0.f;
  int stride = gridDim.x * blockDim.x;
  for (int i = blockIdx.x * blockDim.x + threadIdx.x; i < n4; i += stride) {
    f32x4 v = *(const f32x4*)(w + (size_t)i * 4);
    s += fabsf(v[0]) + fabsf(v[1]) + fabsf(v[2]) + fabsf(v[3]);
  }
#pragma unroll
  for (int off = 32; off > 0; off >>= 1) s += __shfl_down(s, off);
  __shared__ float sm[4];
  int lane = threadIdx.x & 63, wid = threadIdx.x >> 6;
  if (lane == 0) sm[wid] = s;
  __syncthreads();
  if (threadIdx.x == 0) partials[blockIdx.x] = (sm[0] + sm[1]) + (sm[2] + sm[3]);
}

__global__ void finalize_kernel(const unsigned* __restrict__ gbits,
                                const float* __restrict__ partials,
                                float* __restrict__ params) {
  __shared__ double sd[256];
  double s = 0.0;
  for (int i = threadIdx.x; i < NPART; i += 256) s += (double)partials[i];
  sd[threadIdx.x] = s;
  __syncthreads();
  for (int h = 128; h > 0; h >>= 1) {
    if (threadIdx.x < h) sd[threadIdx.x] += sd[threadIdx.x + h];
    __syncthreads();
  }
  if (threadIdx.x == 0) {
    float beta  = fmaxf((float)(sd[0] / (double)NW), 1e-5f);
    float gamma = fmaxf(__uint_as_float(gbits[0]), 1e-5f);
    params[0] = 128.0f / gamma;          // activation scale (q/gamma)
    params[1] = beta;                    // weight divisor
    params[2] = beta * gamma / 128.0f;   // output rescale
  }
}

// ---------------- quantization (int8 outputs, linear layouts) ----------------

__global__ void quant_x_kernel(const float* __restrict__ x,
                               char* __restrict__ xq,
                               const float* __restrict__ params, int n16) {
  float s = params[0];
  int stride = gridDim.x * blockDim.x;
  for (int i = blockIdx.x * blockDim.x + threadIdx.x; i < n16; i += stride) {
    const f32x4* p = (const f32x4*)(x + (size_t)i * 16);
    s8x16 o;
#pragma unroll
    for (int v = 0; v < 4; ++v) {
      f32x4 t = p[v];
#pragma unroll
      for (int k = 0; k < 4; ++k) {
        float r = fminf(fmaxf(rintf(t[k] * s), -128.f), 127.f);
        o[v * 4 + k] = (char)(int)r;
      }
    }
    *(s8x16*)(xq + (size_t)i * 16) = o;
  }
}

__global__ void quant_w_kernel(const float* __restrict__ w,
                               char* __restrict__ wq,
                               const float* __restrict__ params, int n16) {
  float beta = params[1];
  int stride = gridDim.x * blockDim.x;
  for (int i = blockIdx.x * blockDim.x + threadIdx.x; i < n16; i += stride) {
    const f32x4* p = (const f32x4*)(w + (size_t)i * 16);
    s8x16 o;
#pragma unroll
    for (int v = 0; v < 4; ++v) {
      f32x4 t = p[v];
#pragma unroll
      for (int k = 0; k < 4; ++k) {
        // round_clip(|w|/beta, -1, 1): nonneg -> {0,1}; IEEE div matches ref rounding
        o[v * 4 + k] = (rintf(fabsf(t[k]) / beta) >= 1.0f) ? (char)1 : (char)0;
      }
    }
    *(s8x16*)(wq + (size_t)i * 16) = o;
  }
}

// ---------------- GEMM: 128x128 tile, BK=128B, 4 waves x 64x64, 2-ring ----
// C[m][n] = sum_k A[m][k] * B[n][k]  (B row-major [N][K] == B^T input)
// Design targets the measured binder (short, barrier-correlated MFMA bursts):
//  - 16 MFMA(32x32x32) per wave per sync section (2x round 9's burst)
//  - ONE barrier + one vmcnt(0) drain per K-tile (drain covers stage(t)
//    issued a full tile earlier -> cheap)
//  - 64 KB LDS -> 2 independent blocks/CU (decorrelated barrier domains)
// Swizzle: LDS[row][s*16..] = global[row][(s^(row&7))*16..]; read granule
// = row&7 -> distinct in every 8-lane group, 2-way across 16 (free, m136).
// A/B frag (validated r9): row=lane&31, k=(lane>>5)*16+byte per 32B window.
// C/D (m74/m101, validated r9): col=lane&31, row=(reg&3)+8*(reg>>2)+4*(lane>>5).

__global__ __launch_bounds__(256, 2) void gemm_kernel(
    const char* __restrict__ A,   // xq int8 [M][K]
    const char* __restrict__ B,   // wq int8 [N][K]
    float* __restrict__ C,        // [M][N] fp32
    const float* __restrict__ params) {
  __shared__ __align__(16) char lds[65536];   // 2 x (A 16K + B 16K)

  const int tid  = threadIdx.x;
  const int lane = tid & 63, wid = tid >> 6;
  const int wm = wid & 1, wn = wid >> 1;      // 2x2 waves, each 64x64
  const int l31 = lane & 31, h = lane >> 5;

  // T1: bijective XCD swizzle (8192 % 8 == 0); XCD c owns m-tiles [c*8,c*8+8)
  // x all 128 n-tiles, m fastest -> 8 m-blocks share each B panel in L2.
  const int wg = (blockIdx.x & 7) * 1024 + (blockIdx.x >> 3);
  const int m0 = ((wg >> 10) * 8 + (wg & 7)) * 128;
  const int n0 = ((wg & 1023) >> 3) * 128;

  // ---- staging: one gload instr = 32 rows x 128B (4KB); thread -> row
  // +(tid>>3), LDS slot tid&7 (linear dest), global slot (tid&7)^(row&7).
  const int csw = ((tid & 7) ^ ((tid >> 3) & 7)) * 16;
  const char* gA = A + (size_t)(m0 + (tid >> 3)) * K + csw;
  const char* gB = B + (size_t)(n0 + (tid >> 3)) * K + csw;
  const int dst = tid * 16;

  auto stage = [&](int t) {
    char* L = lds + (t & 1) * 32768;
    const size_t ko = (size_t)t * 128;
#pragma unroll
    for (int j = 0; j < 4; ++j) {
      __builtin_amdgcn_global_load_lds((const GAS void*)(gA + ko + (size_t)j * 32 * K),
                                       (LAS void*)(L + j * 4096 + dst), 16, 0, 0);
      __builtin_amdgcn_global_load_lds((const GAS void*)(gB + ko + (size_t)j * 32 * K),
                                       (LAS void*)(L + 16384 + j * 4096 + dst), 16, 0, 0);
    }
  };

  // ---- fragment read offsets: global slot g=ks*2+h of row -> LDS slot
  // g^(row&7); row = base32 + l31 so row&7 = l31&7.
  int aoff[2][4], boff[2][4];
#pragma unroll
  for (int f = 0; f < 2; ++f)
#pragma unroll
    for (int ks = 0; ks < 4; ++ks) {
      const int sw = (((ks * 2 + h) ^ (l31 & 7)) * 16);
      aoff[f][ks] = (wm * 64 + f * 32 + l31) * 128 + sw;
      boff[f][ks] = 16384 + (wn * 64 + f * 32 + l31) * 128 + sw;
    }

  i32x16 acc[2][2] = {};

  // prologue: tile 0 staged
  stage(0);

  for (int t = 0; t < NKT; ++t) {
    const char* buf = lds + (t & 1) * 32768;
    // drain: stage(t) (issued one full tile ago, except t=0) complete.
    asm volatile("s_waitcnt vmcnt(0)" ::: "memory");
    SBAR;
    // barrier: all waves' tile-t shares resident; all waves' tile-(t-1)
    // reads retired (issued before their stage(t) last iter) -> staging
    // buf[(t+1)&1] (= tile t-1's buffer) below is race-free.
    __builtin_amdgcn_s_barrier();
    SBAR;
    i32x4 af[2][4], bf[2][4];
#pragma unroll
    for (int f = 0; f < 2; ++f)
#pragma unroll
      for (int ks = 0; ks < 4; ++ks) {
        af[f][ks] = *(const i32x4*)(buf + aoff[f][ks]);
        bf[f][ks] = *(const i32x4*)(buf + boff[f][ks]);
      }
    if (t + 1 < NKT) stage(t + 1);   // other buffer; overlaps MFMA below
    __builtin_amdgcn_s_setprio(1);
#pragma unroll
    for (int ks = 0; ks < 4; ++ks)
#pragma unroll
      for (int fm = 0; fm < 2; ++fm)
#pragma unroll
        for (int fn = 0; fn < 2; ++fn)
          acc[fm][fn] = __builtin_amdgcn_mfma_i32_32x32x32_i8(af[fm][ks], bf[fn][ks], acc[fm][fn], 0, 0, 0);
    __builtin_amdgcn_s_setprio(0);
  }

  // epilogue: C/D 32x32 layout: col = lane&31, row = (reg&3)+8*(reg>>2)+4*h
  const float sc = params[2];
#pragma unroll
  for (int fm = 0; fm < 2; ++fm)
#pragma unroll
    for (int fn = 0; fn < 2; ++fn) {
      const int crow = m0 + wm * 64 + fm * 32 + h * 4;
      const int ccol = n0 + wn * 64 + fn * 32 + l31;
#pragma unroll
      for (int r = 0; r < 16; ++r) {
        const int row = crow + (r & 3) + 8 * (r >> 2);
        C[(size_t)row * N + ccol] = (float)acc[fm][fn][r] * sc;
      }
    }
}

// ---------------- launch ----------------

extern "C" void kernel_launch(void* const* d_in, const int* in_sizes, int n_in,
                              void* d_out, int out_size, void* d_ws, size_t ws_size,
                              hipStream_t stream) {
  const float* x = (const float*)d_in[0];
  const float* w = (const float*)d_in[1];
  float* out = (float*)d_out;
  char* ws = (char*)d_ws;

  unsigned* gamma_bits = (unsigned*)ws;            // 4 B
  float*    params     = (float*)(ws + 16);        // 3 floats
  float*    partials   = (float*)(ws + 256);       // 2048 floats
  char*     xq = ws + 16384;                       // 33,554,432 B
  char*     wq = ws + 16384 + (size_t)NX;          // 67,108,864 B

  hipMemsetAsync(ws, 0, 256, stream);  // zero gamma accumulator each call

  reduce_absmax_kernel<<<NPART, 256, 0, stream>>>(x, gamma_bits, (int)(NX / 4));
  reduce_abssum_kernel<<<NPART, 256, 0, stream>>>(w, partials, (int)(NW / 4));
  finalize_kernel<<<1, 256, 0, stream>>>(gamma_bits, partials, params);
  quant_x_kernel<<<2048, 256, 0, stream>>>(x, xq, params, (int)(NX / 16));
  quant_w_kernel<<<2048, 256, 0, stream>>>(w, wq, params, (int)(NW / 16));

  gemm_kernel<<<8192, 256, 0, stream>>>(xq, wq, out, params);
}